// Round 1
// baseline (110.885 us; speedup 1.0000x reference)
//
#include <hip/hip_runtime.h>

#define NROWS 2048
#define MLEN  3000
#define LPAD  4096
#define PAD0  548
#define NLVL  8
#define NT    256

__global__ __launch_bounds__(NT) void despawn_kernel(
    const float* __restrict__ x,
    const float* __restrict__ scaling,
    const float* __restrict__ scaling_rec,
    float* __restrict__ recon_out,
    float* __restrict__ coef_out)
{
    __shared__ float bufA[LPAD];        // 16 KB
    __shared__ float bufB[LPAD / 2];    // 8 KB
    __shared__ float coef[LPAD];        // 16 KB -- exactly the coeffs output layout
    __shared__ float fsca[NLVL * 8];
    __shared__ float fwav[NLVL * 8];

    const int tid = threadIdx.x;
    const int row = blockIdx.x;

    // Build filters: sca[lvl][k] = scaling[lvl][k]
    //                wav[lvl][k] = scaling_rec[lvl][7-k] * ((k odd) ? -1 : +1)  (_make_wavelet)
    if (tid < NLVL * 8) {
        const int lvl = tid >> 3, k = tid & 7;
        fsca[tid] = scaling[tid];
        fwav[tid] = scaling_rec[lvl * 8 + (7 - k)] * ((k & 1) ? -1.0f : 1.0f);
    }

    // Load row with edge padding (pad mode='edge': clamp index)
    const float* xr = x + (size_t)row * MLEN;
    for (int i = tid; i < LPAD; i += NT) {
        int j = i - PAD0;
        j = j < 0 ? 0 : (j > MLEN - 1 ? MLEN - 1 : j);
        bufA[i] = xr[j];
    }
    __syncthreads();

    // ---------------- analysis ----------------
    // details[j] = sum_k in[(2j-k) mod M] * wav[k]   (circular conv then [::2])
    // approx [j] = sum_k in[(2j-k) mod M] * sca[k]
    float* cur = bufA;
    float* alt = bufB;
    int   Ml  = LPAD;
    int   coff = 0;
    for (int lvl = 0; lvl < NLVL; ++lvl) {
        const int half = Ml >> 1;
        const int mask = Ml - 1;
        const float* w = &fwav[lvl * 8];
        const float* s = &fsca[lvl * 8];
        for (int j = tid; j < half; j += NT) {
            const int b = 2 * j;
            float ds = 0.0f, as = 0.0f;
#pragma unroll
            for (int k = 0; k < 8; ++k) {
                const float v = cur[(b - k) & mask];
                ds = fmaf(v, w[k], ds);
                as = fmaf(v, s[k], as);
            }
            coef[coff + j] = ds;
            alt[j] = as;
        }
        __syncthreads();
        coff += half;
        float* t = cur; cur = alt; alt = t;
        Ml = half;
    }
    // final approx (len 16) sits in `cur` (= bufA after 8 swaps); append to coef
    if (tid < 16) coef[LPAD - 16 + tid] = cur[tid];
    __syncthreads();

    // ---------------- synthesis ----------------
    // out[n] = sum_{k parity==n parity} ( d[((n+k)/2) mod len]*wav[k]
    //                                   + a[((n+k)/2) mod len]*sca[k] )
    // (upsample2 + circular correlation, polyphase form)
    const float* a = &coef[LPAD - 16];
    int len = 16;
    float* obuf = bufB;   // 32,64,128,...,2048 alternate bufB/bufA; final 4096 -> bufA
    for (int lvl = NLVL - 1; lvl >= 0; --lvl) {
        const int Mout  = len << 1;
        const int lmask = len - 1;
        const float* d = &coef[LPAD - (LPAD >> lvl)];
        const float* w = &fwav[lvl * 8];
        const float* s = &fsca[lvl * 8];
        for (int n = tid; n < Mout; n += NT) {
            const int p = n & 1;
            float sum = 0.0f;
#pragma unroll
            for (int t4 = 0; t4 < 4; ++t4) {
                const int k   = p + 2 * t4;
                const int idx = ((n + k) >> 1) & lmask;
                sum = fmaf(d[idx], w[k], sum);
                sum = fmaf(a[idx], s[k], sum);
            }
            obuf[n] = sum;
        }
        __syncthreads();
        a   = obuf;
        len = Mout;
        obuf = (obuf == bufB) ? bufA : bufB;
    }
    // a == bufA, length 4096 reconstruction

    // ---------------- stores ----------------
    float* ro = recon_out + (size_t)row * MLEN;
    for (int i = tid; i < MLEN; i += NT) ro[i] = a[PAD0 + i];

    float* co = coef_out + (size_t)row * LPAD;
    for (int i = tid; i < LPAD; i += NT) co[i] = coef[i];
}

extern "C" void kernel_launch(void* const* d_in, const int* in_sizes, int n_in,
                              void* d_out, int out_size, void* d_ws, size_t ws_size,
                              hipStream_t stream) {
    const float* x           = (const float*)d_in[0];
    const float* scaling     = (const float*)d_in[1];
    const float* scaling_rec = (const float*)d_in[2];
    float* recon = (float*)d_out;                       // 2048*3000 floats
    float* coefo = recon + (size_t)NROWS * MLEN;        // 2048*4096 floats
    despawn_kernel<<<dim3(NROWS), dim3(NT), 0, stream>>>(x, scaling, scaling_rec,
                                                         recon, coefo);
    (void)in_sizes; (void)n_in; (void)out_size; (void)d_ws; (void)ws_size;
}